// Round 8
// baseline (166.354 us; speedup 1.0000x reference)
//
#include <hip/hip_runtime.h>
#include <hip/hip_bf16.h>

using u16 = unsigned short;
using u32 = unsigned int;

typedef __bf16 bf16x8 __attribute__((ext_vector_type(8)));
typedef float f32x4 __attribute__((ext_vector_type(4)));

__device__ __forceinline__ u16 f2bf(float f) {
  union { float f; u32 u; } c; c.f = f;
  u32 u = c.u;
  u32 r = u + 0x7fffu + ((u >> 16) & 1u);   // RNE
  return (u16)(r >> 16);
}
__device__ __forceinline__ float bf2f(u16 h) {
  return __uint_as_float((u32)h << 16);
}
__device__ __forceinline__ u32 pack2(float a, float b) {
  return (u32)f2bf(a) | ((u32)f2bf(b) << 16);
}
// split v into bf16 hi + bf16 lo (v ~= hi + lo, error ~2^-18 |v|)
__device__ __forceinline__ void bsplit(float v, u16& hi, u16& lo) {
  hi = f2bf(v);
  lo = f2bf(v - bf2f(hi));
}

constexpr int Bb  = 64;    // graphs
constexpr int L   = 1024;  // nodes/graph
constexpr int IN  = 128;
constexpr int OUT = 128;
constexpr int FLR = 64;
constexpr int N   = Bb * L;

// ---------------------------------------------------------------------------
// k_pack: one-time weight repack into MFMA B-fragment order (bf16). UNCHANGED.
// ---------------------------------------------------------------------------
__global__ __launch_bounds__(256) void k_pack(
    const float* __restrict__ Wout, const float* __restrict__ Wh,
    u16* __restrict__ Bp, u16* __restrict__ Whp)
{
  const int blk = blockIdx.x;
  if (blk < 16) {
    int t2 = blk * 256 + threadIdx.x;    // 0..4095 frag-lanes
    int lane = t2 & 63, kstep = (t2 >> 6) & 7, ntile = t2 >> 9;
    int n  = ntile * 16 + (lane & 15);
    int kb = kstep * 32 + (lane >> 4) * 8;
    u16* dst = Bp + (size_t)t2 * 8;
#pragma unroll
    for (int j = 0; j < 8; ++j) dst[j] = f2bf(Wout[(kb + j) * OUT + n]);
  } else {
#pragma unroll
    for (int i = 0; i < 4; ++i) {
      int t2 = i * 256 + threadIdx.x;    // 0..1023 frag-lanes
      int l = t2 & 63, ks = (t2 >> 6) & 3, nt = t2 >> 8;
      int kb = ks * 32 + (l >> 4) * 8;
      u16* dst = Whp + (size_t)t2 * 8;
#pragma unroll
      for (int j = 0; j < 8; ++j)
        dst[j] = f2bf(Wh[(size_t)(kb + j) * FLR + nt * 16 + (l & 15)]);
    }
  }
}

// ---------------------------------------------------------------------------
// k_sh: UNCHANGED (passing).
// ---------------------------------------------------------------------------
__global__ __launch_bounds__(256) void k_sh(
    const float* __restrict__ x, const float* __restrict__ Ws, const float* __restrict__ bs,
    const u16* __restrict__ Whp, const float* __restrict__ bh,
    float* __restrict__ s_buf, u16* __restrict__ h_buf, u16* __restrict__ xbf)
{
  __shared__ alignas(16) u16 whl[128 * 64];   // 16 KB: Wh bf16 frags

  const int tid = threadIdx.x;
  {
    const uint4* __restrict__ src = (const uint4*)Whp;
    uint4* dstl = (uint4*)whl;
#pragma unroll
    for (int i = 0; i < 4; ++i) {
      int idx = i * 256 + tid;
      dstl[idx] = src[idx];
    }
  }

  const int blk = blockIdx.x;
  const int lane = tid & 63;
  const int w = __builtin_amdgcn_readfirstlane(tid >> 6);
  const int mb = blk * 64 + w * 16;        // m-tile base node
  const int col = lane & 15;
  const int kq  = lane >> 4;               // 0..3
  const int mrow = mb + col;               // this lane's A row

  const float* xr = x + (size_t)mrow * IN;

  float sp0 = 0.f, sp1 = 0.f, sp2 = 0.f, sp3 = 0.f;
  bf16x8 a[4];
#pragma unroll
  for (int ks = 0; ks < 4; ++ks) {
    float4 xa = *(const float4*)(xr + ks * 32 + kq * 8);
    float4 xb = *(const float4*)(xr + ks * 32 + kq * 8 + 4);
    float xf[8] = {xa.x, xa.y, xa.z, xa.w, xb.x, xb.y, xb.z, xb.w};
#pragma unroll
    for (int j = 0; j < 8; ++j) {
      const float4 wsr = *(const float4*)(Ws + (size_t)(ks * 32 + kq * 8 + j) * 4);
      sp0 = fmaf(xf[j], wsr.x, sp0);
      sp1 = fmaf(xf[j], wsr.y, sp1);
      sp2 = fmaf(xf[j], wsr.z, sp2);
      sp3 = fmaf(xf[j], wsr.w, sp3);
    }
    union { __hip_bfloat162 h2[4]; bf16x8 v; } cv;
    cv.h2[0] = __float22bfloat162_rn(float2{xf[0], xf[1]});
    cv.h2[1] = __float22bfloat162_rn(float2{xf[2], xf[3]});
    cv.h2[2] = __float22bfloat162_rn(float2{xf[4], xf[5]});
    cv.h2[3] = __float22bfloat162_rn(float2{xf[6], xf[7]});
    a[ks] = cv.v;
  }

  if (xbf) {
#pragma unroll
    for (int ks = 0; ks < 4; ++ks)
      *(bf16x8*)(xbf + (((size_t)(blk * 4 + w) * 4 + ks) * 64 + lane) * 8) = a[ks];
  }

  sp0 += __shfl_xor(sp0, 16, 64); sp0 += __shfl_xor(sp0, 32, 64);
  sp1 += __shfl_xor(sp1, 16, 64); sp1 += __shfl_xor(sp1, 32, 64);
  sp2 += __shfl_xor(sp2, 16, 64); sp2 += __shfl_xor(sp2, 32, 64);
  sp3 += __shfl_xor(sp3, 16, 64); sp3 += __shfl_xor(sp3, 32, 64);
  if (kq == 0) {
    float4 sv;
    sv.x = sp0 + bs[0]; sv.y = sp1 + bs[1];
    sv.z = sp2 + bs[2]; sv.w = sp3 + bs[3];
    *(float4*)(s_buf + (size_t)mrow * 4) = sv;
  }

  __syncthreads();   // whl ready

  f32x4 acc[4];
#pragma unroll
  for (int nt = 0; nt < 4; ++nt) acc[nt] = f32x4{0.f, 0.f, 0.f, 0.f};

  const bf16x8* __restrict__ wf = (const bf16x8*)whl;
#pragma unroll
  for (int nt = 0; nt < 4; ++nt) {
#pragma unroll
    for (int ks = 0; ks < 4; ++ks) {
      acc[nt] = __builtin_amdgcn_mfma_f32_16x16x32_bf16(
          a[ks], wf[(nt * 4 + ks) * 64 + lane], acc[nt], 0, 0, 0);
    }
  }

#pragma unroll
  for (int nt = 0; nt < 4; ++nt) {
    float bias = bh[nt * 16 + col];
#pragma unroll
    for (int r = 0; r < 4; ++r) {
      float v = acc[nt][r] + bias;
      h_buf[(size_t)(mb + kq * 4 + r) * FLR + nt * 16 + col] = f2bf(v);
    }
  }
}

// ---------------------------------------------------------------------------
// k_fused — ROUND 8: same math as round 7 (MFMA distances, bit-identical
// output), stalls removed:
//  (1) apack TILE-MAJOR: chunk = tile*32 + kq*16 + col -> the wave's 32
//      active lanes read 32 consecutive 16B chunks (conflict-free b128
//      pattern, same as k_sh's wf reads). R7's (cand*32 + kq*16) stride-32B
//      pattern was 4-way conflicted (655K conflict cycles).
//  (2) 1-deep software pipeline: prefetch tile t+1's A-frag and issue its 2
//      MFMAs BEFORE tile t's 64-fmed3 ladder -> ladder (~130 cy) hides both
//      the ds_read (~120 cy) and MFMA latency. R7 ran these serially.
//  (3) agg gather: 2 passes of (issue 8 uint4 loads, then accumulate 8) --
//      8 loads in flight instead of ~2; capped at 8 to stay <128 VGPR.
//  (4) GEMM A-frags (xbf) issued right after phase-1; vmcnt waits land 4
//      barriers later in the GEMM.
// ---------------------------------------------------------------------------
__global__ __launch_bounds__(512) void k_fused(
    const float* __restrict__ s_buf, const u16* __restrict__ h_buf,
    const float* __restrict__ x, const u16* __restrict__ Bp,
    const u16* __restrict__ xbf,
    const float* __restrict__ bout, float* __restrict__ out)
{
  __shared__ alignas(16) float lists[8 * 64 * 17];   // 8704 floats (34816 B)
  __shared__ float fk[64 * 17];                      // final 16 keys per node
  u16* agg_lds = (u16*)lists;          // [64][136] bf16, bytes [0, 17408)
  u16* apack   = (u16*)lists;          // 2048 chunks x 8 u16, bytes [0, 32768)
  float* wk = lists + 4608;            // [64*17] f32 weights (dead region at write)

  const int lane = threadIdx.x & 63;
  const int w = __builtin_amdgcn_readfirstlane(threadIdx.x >> 6);
  const int g = blockIdx.y;
  const int nb0 = blockIdx.x * 64;

  // ---- phase A: pack candidate rows into LDS, tile-major (2 cands/thread)
  {
    const float4* __restrict__ sgf = (const float4*)(s_buf + (size_t)g * L * 4);
#pragma unroll
    for (int i = 0; i < 2; ++i) {
      int c = threadIdx.x + i * 512;
      float4 s = sgf[c];
      float sq = fmaf(s.w, s.w, fmaf(s.z, s.z, fmaf(s.y, s.y, s.x * s.x)));
      u16 xh,xl,yh,yl,zh,zl,wh,wl,qh,ql;
      bsplit(s.x, xh, xl); bsplit(s.y, yh, yl);
      bsplit(s.z, zh, zl); bsplit(s.w, wh, wl);
      bsplit(sq,  qh, ql);
      union { u16 r[16]; uint4 v[2]; } ru;
      ru.r[0]=xh; ru.r[1]=yh; ru.r[2]=zh;  ru.r[3]=wh;
      ru.r[4]=xl; ru.r[5]=yl; ru.r[6]=zl;  ru.r[7]=wl;
      ru.r[8]=qh; ru.r[9]=ql; ru.r[10]=0x3F80u; ru.r[11]=0x3F80u;
      ru.r[12]=0; ru.r[13]=0; ru.r[14]=0;  ru.r[15]=0;
      const int T = c >> 4, cc = c & 15;
      *(uint4*)(apack + (T * 32 + cc) * 8)      = ru.v[0];   // k0-7
      *(uint4*)(apack + (T * 32 + 16 + cc) * 8) = ru.v[1];   // k8-15
    }
  }

  // ---- phase B: per-lane query B-fragments (registers) — unchanged from R7
  const int col = lane & 15;
  const int kq  = lane >> 4;
  const int qt  = w & 3;                  // query tile (16 nodes)
  const int ch  = w >> 2;                 // candidate half (512 cands)
  const int nodeL = qt * 16 + col;        // this lane's query node (0..63)

  union { u16 r[8]; bf16x8 v; } b1u, b2u;
#pragma unroll
  for (int i = 0; i < 8; ++i) { b1u.r[i] = 0; b2u.r[i] = 0; }
  {
    float4 si = *(const float4*)(s_buf + (size_t)(g * L + nb0 + nodeL) * 4);
    float sqi = fmaf(si.w, si.w, fmaf(si.z, si.z, fmaf(si.y, si.y, si.x * si.x)));
    u16 xh,xl,yh,yl,zh,zl,wh,wl,qh,ql;
    bsplit(si.x, xh, xl); bsplit(si.y, yh, yl);
    bsplit(si.z, zh, zl); bsplit(si.w, wh, wl);
    bsplit(sqi,  qh, ql);
    if (kq == 0) {
      b1u.r[0] = f2bf(-2.0f * bf2f(xh)); b1u.r[1] = f2bf(-2.0f * bf2f(yh));
      b1u.r[2] = f2bf(-2.0f * bf2f(zh)); b1u.r[3] = f2bf(-2.0f * bf2f(wh));
      b1u.r[4] = b1u.r[0]; b1u.r[5] = b1u.r[1];
      b1u.r[6] = b1u.r[2]; b1u.r[7] = b1u.r[3];
      b2u.r[0] = f2bf(-2.0f * bf2f(xl)); b2u.r[1] = f2bf(-2.0f * bf2f(yl));
      b2u.r[2] = f2bf(-2.0f * bf2f(zl)); b2u.r[3] = f2bf(-2.0f * bf2f(wl));
    } else if (kq == 1) {
      b1u.r[0] = 0x3F80u; b1u.r[1] = 0x3F80u;   // pair with A's sqj_hi/lo
      b1u.r[2] = qh;      b1u.r[3] = ql;        // sqi via A's 1.0 slots
    }
  }

  __syncthreads();   // apack ready

  // ---- phase 1: pipelined 32 tiles — prefetch(t+1)+MFMA(t+1) before ladder(t)
  float b[16];
#pragma unroll
  for (int k = 0; k < 16; ++k) b[k] = 3.0e38f;

  union { u16 r[8]; bf16x8 v; } zu;
#pragma unroll
  for (int i = 0; i < 8; ++i) zu.r[i] = 0;

  const int cbase0 = ch * 512;
  const int tile0  = ch * 32;
  const int rdoff  = kq * 16 + col;       // chunk offset within a tile

  bf16x8 avP = zu.v;
  if (kq < 2) avP = *(const bf16x8*)(apack + (tile0 * 32 + rdoff) * 8);
  f32x4 accP = __builtin_amdgcn_mfma_f32_16x16x32_bf16(avP, b2u.v,
                   f32x4{0.f, 0.f, 0.f, 0.f}, 0, 0, 0);
  accP = __builtin_amdgcn_mfma_f32_16x16x32_bf16(avP, b1u.v, accP, 0, 0, 0);

#pragma unroll 4
  for (int tc = 0; tc < 32; ++tc) {
    f32x4 accC = accP;
    if (tc + 1 < 32) {                    // issue next tile before the ladder
      bf16x8 avN = zu.v;
      if (kq < 2) avN = *(const bf16x8*)(apack + ((tile0 + tc + 1) * 32 + rdoff) * 8);
      f32x4 t = __builtin_amdgcn_mfma_f32_16x16x32_bf16(avN, b2u.v,
                    f32x4{0.f, 0.f, 0.f, 0.f}, 0, 0, 0);
      accP = __builtin_amdgcn_mfma_f32_16x16x32_bf16(avN, b1u.v, t, 0, 0, 0);
    }
    const int cbk = cbase0 + tc * 16 + kq * 4;
#pragma unroll
    for (int r = 0; r < 4; ++r) {
      u32 db = __float_as_uint(accC[r]);
      float key = __uint_as_float((db & 0xFFFFFC00u) | (u32)(cbk + r));
#pragma unroll
      for (int k = 15; k >= 1; --k) b[k] = __builtin_amdgcn_fmed3f(key, b[k - 1], b[k]);
      b[0] = fminf(key, b[0]);
    }
  }

  // ---- early-issue GEMM A-frags (global, independent of all LDS phases)
  const int mt  = w & 3;
  const int tileA = (g * 16 + blockIdx.x) * 4 + mt;
  bf16x8 aAr[4];
  if (xbf) {
#pragma unroll
    for (int ks = 0; ks < 4; ++ks)
      aAr[ks] = *(const bf16x8*)(xbf + (((size_t)tileA * 4 + ks) * 64 + lane) * 8);
  }

  __syncthreads();   // all apack reads done before lists overwrite

  // ---- dump partial lists: slot (src, node)
  {
    const int src = ch * 4 + kq;
#pragma unroll
    for (int k = 0; k < 16; ++k) lists[(src * 64 + nodeL) * 17 + k] = b[k];
  }
  __syncthreads();

  // ---- merge tree (unchanged)
  float c[16];
  if (w < 4) {
#pragma unroll
    for (int i = 0; i < 16; ++i)
      c[i] = fminf(lists[(w * 64 + lane) * 17 + i],
                   lists[((w + 4) * 64 + lane) * 17 + (15 - i)]);
#pragma unroll
    for (int dd = 8; dd >= 1; dd >>= 1) {
#pragma unroll
      for (int i = 0; i < 16; ++i) {
        if ((i & dd) == 0) {
          float lo = fminf(c[i], c[i | dd]);
          float hi = fmaxf(c[i], c[i | dd]);
          c[i] = lo; c[i | dd] = hi;
        }
      }
    }
#pragma unroll
    for (int k = 0; k < 16; ++k) lists[(w * 64 + lane) * 17 + k] = c[k];
  }
  __syncthreads();
  if (w < 2) {
#pragma unroll
    for (int i = 0; i < 16; ++i)
      c[i] = fminf(c[i], lists[((w + 2) * 64 + lane) * 17 + (15 - i)]);
#pragma unroll
    for (int dd = 8; dd >= 1; dd >>= 1) {
#pragma unroll
      for (int i = 0; i < 16; ++i) {
        if ((i & dd) == 0) {
          float lo = fminf(c[i], c[i | dd]);
          float hi = fmaxf(c[i], c[i | dd]);
          c[i] = lo; c[i | dd] = hi;
        }
      }
    }
#pragma unroll
    for (int k = 0; k < 16; ++k) lists[(w * 64 + lane) * 17 + k] = c[k];
  }
  __syncthreads();
  if (w == 0) {
#pragma unroll
    for (int i = 0; i < 16; ++i) {
      float o = lists[(64 + lane) * 17 + (15 - i)];
      float kf = fminf(c[i], o);
      fk[lane * 17 + i] = kf;
      wk[lane * 17 + i] =
          __expf(-10.0f * __uint_as_float(__float_as_uint(kf) & 0xFFFFFC00u));
    }
  }
  __syncthreads();        // fk/wk ready; lists[] selection data dead

  // ---- aggregation: 2 passes of (prefetch 8 gathers, accumulate 8)
  {
    const int q     = lane & 7;              // dim chunk (8 bf16 = 16 B)
    const int nodeA = w * 8 + (lane >> 3);   // 0..63
    const u16* __restrict__ hg = h_buf + (size_t)g * L * FLR;

    float m[8], xx[8];
#pragma unroll
    for (int j = 0; j < 8; ++j) { m[j] = 0.f; xx[j] = -3.0e38f; }

#pragma unroll
    for (int half = 0; half < 2; ++half) {
      u32 ui[8]; float wgt[8]; uint4 hv[8];
#pragma unroll
      for (int k = 0; k < 8; ++k) {
        int kk = half * 8 + k;
        ui[k]  = __float_as_uint(fk[nodeA * 17 + kk]) & 1023u;
        wgt[k] = wk[nodeA * 17 + kk];
      }
#pragma unroll
      for (int k = 0; k < 8; ++k)
        hv[k] = ((const uint4*)(hg + (size_t)ui[k] * FLR))[q];
#pragma unroll
      for (int k = 0; k < 8; ++k) {
        u32 p[4] = {hv[k].x, hv[k].y, hv[k].z, hv[k].w};
        float wg = wgt[k];
#pragma unroll
        for (int d = 0; d < 4; ++d) {
          float lo = __uint_as_float(p[d] << 16) * wg;
          float hi = __uint_as_float(p[d] & 0xFFFF0000u) * wg;
          m[2 * d]     += lo;  xx[2 * d]     = fmaxf(xx[2 * d], lo);
          m[2 * d + 1] += hi;  xx[2 * d + 1] = fmaxf(xx[2 * d + 1], hi);
        }
      }
    }

    uint4 om, ox;
    om.x = pack2(m[0] * 0.0625f, m[1] * 0.0625f);
    om.y = pack2(m[2] * 0.0625f, m[3] * 0.0625f);
    om.z = pack2(m[4] * 0.0625f, m[5] * 0.0625f);
    om.w = pack2(m[6] * 0.0625f, m[7] * 0.0625f);
    ox.x = pack2(xx[0], xx[1]); ox.y = pack2(xx[2], xx[3]);
    ox.z = pack2(xx[4], xx[5]); ox.w = pack2(xx[6], xx[7]);
    *(uint4*)(&agg_lds[nodeA * 136 + q * 8])       = om;
    *(uint4*)(&agg_lds[nodeA * 136 + FLR + q * 8]) = ox;
  }
  __syncthreads();

  // ---- output GEMM (A-frags already in aAr)
  const int ntb = (w >> 2) * 4;
  const int rowL = mt * 16 + (lane & 15);
  const int grow = g * L + nb0 + rowL;
  const int kq8 = (lane >> 4) * 8;

  f32x4 acc[4];
#pragma unroll
  for (int nt = 0; nt < 4; ++nt) acc[nt] = f32x4{0.f, 0.f, 0.f, 0.f};

  const float* xr = x + (size_t)grow * IN;
  const bf16x8* __restrict__ bp = (const bf16x8*)Bp;

#pragma unroll
  for (int ks = 0; ks < 8; ++ks) {
    bf16x8 a;
    if (ks < 4) {
      if (xbf) {
        a = aAr[ks];
      } else {
        float4 xa = *(const float4*)(xr + ks * 32 + kq8);
        float4 xb = *(const float4*)(xr + ks * 32 + kq8 + 4);
        union { __hip_bfloat162 h2[4]; bf16x8 v; } cv;
        cv.h2[0] = __float22bfloat162_rn(float2{xa.x, xa.y});
        cv.h2[1] = __float22bfloat162_rn(float2{xa.z, xa.w});
        cv.h2[2] = __float22bfloat162_rn(float2{xb.x, xb.y});
        cv.h2[3] = __float22bfloat162_rn(float2{xb.z, xb.w});
        a = cv.v;
      }
    } else {
      a = *(const bf16x8*)(&agg_lds[rowL * 136 + (ks - 4) * 32 + kq8]);
    }
#pragma unroll
    for (int nt = 0; nt < 4; ++nt) {
      bf16x8 bb = bp[((ntb + nt) * 8 + ks) * 64 + lane];
      acc[nt] = __builtin_amdgcn_mfma_f32_16x16x32_bf16(a, bb, acc[nt], 0, 0, 0);
    }
  }

  const int rbase = (lane >> 4) * 4;
  const int colO = lane & 15;
  const int mrow = g * L + nb0 + mt * 16;
#pragma unroll
  for (int nt = 0; nt < 4; ++nt) {
    float bias = bout[(ntb + nt) * 16 + colO];
#pragma unroll
    for (int r = 0; r < 4; ++r) {
      float v = acc[nt][r] + bias;
      out[(size_t)(mrow + rbase + r) * OUT + (ntb + nt) * 16 + colO] = fmaxf(v, 0.0f);
    }
  }
}

extern "C" void kernel_launch(void* const* d_in, const int* in_sizes, int n_in,
                              void* d_out, int out_size, void* d_ws, size_t ws_size,
                              hipStream_t stream) {
  const float* x    = (const float*)d_in[0];
  const float* Ws   = (const float*)d_in[1];
  const float* bs   = (const float*)d_in[2];
  const float* Wh   = (const float*)d_in[3];
  const float* bh   = (const float*)d_in[4];
  const float* Wout = (const float*)d_in[5];
  const float* bout = (const float*)d_in[6];
  float* out = (float*)d_out;

  char* ws = (char*)d_ws;
  float* s_buf = (float*)ws;                                      // 1 MiB
  u16*   h_buf = (u16*)(ws + (1 << 20));                          // 8 MiB
  u16*   Bp    = (u16*)(ws + (1 << 20) + (8 << 20));              // 64 KiB
  u16*   Whp   = (u16*)(ws + (1 << 20) + (8 << 20) + (64 << 10)); // 16 KiB
  u16*   xbf   = (ws_size >= (26u << 20)) ? (u16*)(ws + (10 << 20)) : nullptr;

  k_pack<<<17, 256, 0, stream>>>(Wout, Wh, Bp, Whp);
  k_sh<<<N / 64, 256, 0, stream>>>(x, Ws, bs, Whp, bh, s_buf, h_buf, xbf);
  dim3 gknn(L / 64, Bb);
  k_fused<<<gknn, 512, 0, stream>>>(s_buf, h_buf, x, Bp, xbf, bout, out);
}

// Round 9
// 158.293 us; speedup vs baseline: 1.0509x; 1.0509x over previous
//
#include <hip/hip_runtime.h>
#include <hip/hip_bf16.h>

using u16 = unsigned short;
using u32 = unsigned int;

typedef __bf16 bf16x8 __attribute__((ext_vector_type(8)));
typedef float f32x4 __attribute__((ext_vector_type(4)));

__device__ __forceinline__ u16 f2bf(float f) {
  union { float f; u32 u; } c; c.f = f;
  u32 u = c.u;
  u32 r = u + 0x7fffu + ((u >> 16) & 1u);   // RNE
  return (u16)(r >> 16);
}
__device__ __forceinline__ u32 pack2(float a, float b) {
  return (u32)f2bf(a) | ((u32)f2bf(b) << 16);
}

constexpr int Bb  = 64;    // graphs
constexpr int L   = 1024;  // nodes/graph
constexpr int IN  = 128;
constexpr int OUT = 128;
constexpr int FLR = 64;
constexpr int N   = Bb * L;

// ---------------------------------------------------------------------------
// k_pack: one-time weight repack into MFMA B-fragment order (bf16). UNCHANGED
// (exact R5 body).
// ---------------------------------------------------------------------------
__global__ __launch_bounds__(256) void k_pack(
    const float* __restrict__ Wout, const float* __restrict__ Wh,
    u16* __restrict__ Bp, u16* __restrict__ Whp)
{
  const int blk = blockIdx.x;
  if (blk < 16) {
    int t2 = blk * 256 + threadIdx.x;    // 0..4095 frag-lanes
    int lane = t2 & 63, kstep = (t2 >> 6) & 7, ntile = t2 >> 9;
    int n  = ntile * 16 + (lane & 15);
    int kb = kstep * 32 + (lane >> 4) * 8;
    u16* dst = Bp + (size_t)t2 * 8;
#pragma unroll
    for (int j = 0; j < 8; ++j) dst[j] = f2bf(Wout[(kb + j) * OUT + n]);
  } else {
#pragma unroll
    for (int i = 0; i < 4; ++i) {
      int t2 = i * 256 + threadIdx.x;    // 0..1023 frag-lanes
      int l = t2 & 63, ks = (t2 >> 6) & 3, nt = t2 >> 8;
      int kb = ks * 32 + (l >> 4) * 8;
      u16* dst = Whp + (size_t)t2 * 8;
#pragma unroll
      for (int j = 0; j < 8; ++j)
        dst[j] = f2bf(Wh[(size_t)(kb + j) * FLR + nt * 16 + (l & 15)]);
    }
  }
}

// ---------------------------------------------------------------------------
// k_sh: exact R5 body + ONE addition: writes sqb[node] = |s|^2 so k_fused's
// distance loop can use the norm-expansion form.
// ---------------------------------------------------------------------------
__global__ __launch_bounds__(256) void k_sh(
    const float* __restrict__ x, const float* __restrict__ Ws, const float* __restrict__ bs,
    const u16* __restrict__ Whp, const float* __restrict__ bh,
    float* __restrict__ s_buf, u16* __restrict__ h_buf, u16* __restrict__ xbf,
    float* __restrict__ sqb)
{
  __shared__ alignas(16) u16 whl[128 * 64];   // 16 KB: Wh bf16 frags

  const int tid = threadIdx.x;
  {
    const uint4* __restrict__ src = (const uint4*)Whp;
    uint4* dstl = (uint4*)whl;
#pragma unroll
    for (int i = 0; i < 4; ++i) {
      int idx = i * 256 + tid;
      dstl[idx] = src[idx];
    }
  }

  const int blk = blockIdx.x;
  const int lane = tid & 63;
  const int w = __builtin_amdgcn_readfirstlane(tid >> 6);
  const int mb = blk * 64 + w * 16;        // m-tile base node
  const int col = lane & 15;
  const int kq  = lane >> 4;               // 0..3
  const int mrow = mb + col;               // this lane's A row

  const float* xr = x + (size_t)mrow * IN;

  float sp0 = 0.f, sp1 = 0.f, sp2 = 0.f, sp3 = 0.f;
  bf16x8 a[4];
#pragma unroll
  for (int ks = 0; ks < 4; ++ks) {
    float4 xa = *(const float4*)(xr + ks * 32 + kq * 8);
    float4 xb = *(const float4*)(xr + ks * 32 + kq * 8 + 4);
    float xf[8] = {xa.x, xa.y, xa.z, xa.w, xb.x, xb.y, xb.z, xb.w};
#pragma unroll
    for (int j = 0; j < 8; ++j) {
      const float4 wsr = *(const float4*)(Ws + (size_t)(ks * 32 + kq * 8 + j) * 4);
      sp0 = fmaf(xf[j], wsr.x, sp0);
      sp1 = fmaf(xf[j], wsr.y, sp1);
      sp2 = fmaf(xf[j], wsr.z, sp2);
      sp3 = fmaf(xf[j], wsr.w, sp3);
    }
    union { __hip_bfloat162 h2[4]; bf16x8 v; } cv;
    cv.h2[0] = __float22bfloat162_rn(float2{xf[0], xf[1]});
    cv.h2[1] = __float22bfloat162_rn(float2{xf[2], xf[3]});
    cv.h2[2] = __float22bfloat162_rn(float2{xf[4], xf[5]});
    cv.h2[3] = __float22bfloat162_rn(float2{xf[6], xf[7]});
    a[ks] = cv.v;
  }

  if (xbf) {
#pragma unroll
    for (int ks = 0; ks < 4; ++ks)
      *(bf16x8*)(xbf + (((size_t)(blk * 4 + w) * 4 + ks) * 64 + lane) * 8) = a[ks];
  }

  sp0 += __shfl_xor(sp0, 16, 64); sp0 += __shfl_xor(sp0, 32, 64);
  sp1 += __shfl_xor(sp1, 16, 64); sp1 += __shfl_xor(sp1, 32, 64);
  sp2 += __shfl_xor(sp2, 16, 64); sp2 += __shfl_xor(sp2, 32, 64);
  sp3 += __shfl_xor(sp3, 16, 64); sp3 += __shfl_xor(sp3, 32, 64);
  if (kq == 0) {
    float4 sv;
    sv.x = sp0 + bs[0]; sv.y = sp1 + bs[1];
    sv.z = sp2 + bs[2]; sv.w = sp3 + bs[3];
    *(float4*)(s_buf + (size_t)mrow * 4) = sv;
    // NEW: |s|^2 for the expansion-form distance (same fma order as k_fused's sqi)
    sqb[mrow] = fmaf(sv.w, sv.w, fmaf(sv.z, sv.z, fmaf(sv.y, sv.y, sv.x * sv.x)));
  }

  __syncthreads();   // whl ready

  f32x4 acc[4];
#pragma unroll
  for (int nt = 0; nt < 4; ++nt) acc[nt] = f32x4{0.f, 0.f, 0.f, 0.f};

  const bf16x8* __restrict__ wf = (const bf16x8*)whl;
#pragma unroll
  for (int nt = 0; nt < 4; ++nt) {
#pragma unroll
    for (int ks = 0; ks < 4; ++ks) {
      acc[nt] = __builtin_amdgcn_mfma_f32_16x16x32_bf16(
          a[ks], wf[(nt * 4 + ks) * 64 + lane], acc[nt], 0, 0, 0);
    }
  }

#pragma unroll
  for (int nt = 0; nt < 4; ++nt) {
    float bias = bh[nt * 16 + col];
#pragma unroll
    for (int r = 0; r < 4; ++r) {
      float v = acc[nt][r] + bias;
      h_buf[(size_t)(mb + kq * 4 + r) * FLR + nt * 16 + col] = f2bf(v);
    }
  }
}

// ---------------------------------------------------------------------------
// k_fused — ROUND 9: exact R5 body (the 67.5 µs best; MFMA-distance arc of
// R7/R8 reverted — it traded 12 µs of VALU for >12 µs of stalls both times).
// ONE change vs R5: the distance inner loop uses the norm-expansion form
//   d2 = (sqi + sq_j) + m2x*sjx + m2y*sjy + m2z*sjz + m2w*sjw
// (1 add + 4 fma = 5 VALU/cand vs 4 sub + 4 fma = 8). sq_j comes from the
// precomputed sqb stream (wave-uniform load, scalar-eligible). Expansion
// rounding error ~1e-7 rel — 1000x below the key-truncation granularity
// (1.2e-4) this kernel already tolerates. Self-distance may round slightly
// negative: still sorts first (correct), index bits intact, weight
// exp(+1e-6) ~= 1 matches the reference's clamped exp(0).
// ---------------------------------------------------------------------------
__global__ __launch_bounds__(512) void k_fused(
    const float* __restrict__ s_buf, const u16* __restrict__ h_buf,
    const float* __restrict__ x, const u16* __restrict__ Bp,
    const u16* __restrict__ xbf, const float* __restrict__ sqb,
    const float* __restrict__ bout, float* __restrict__ out)
{
  __shared__ alignas(16) float lists[8 * 64 * 17];   // 8704 floats (34816 B)
  __shared__ float fk[64 * 17];                      // final 16 keys per node
  u16* agg_lds = (u16*)lists;          // [64][136] bf16, bytes [0, 17408)
  float* wk = lists + 4608;            // [64*17] f32 weights (dead region at write)

  const int lane = threadIdx.x & 63;
  const int w = __builtin_amdgcn_readfirstlane(threadIdx.x >> 6);
  const int g = blockIdx.y;
  const int nb0 = blockIdx.x * 64;
  const int node = g * L + nb0 + lane;

  const float4 si = *(const float4*)(s_buf + (size_t)node * 4);
  const float4* __restrict__ sg = (const float4*)(s_buf + (size_t)g * L * 4);
  const float*  __restrict__ sqg = sqb + (size_t)g * L;
  const int jb = __builtin_amdgcn_readfirstlane(w * 128);

  const float m2x = -2.0f * si.x, m2y = -2.0f * si.y;
  const float m2z = -2.0f * si.z, m2w = -2.0f * si.w;
  const float sqi = fmaf(si.w, si.w, fmaf(si.z, si.z, fmaf(si.y, si.y, si.x * si.x)));

  float b[16];
#pragma unroll
  for (int k = 0; k < 16; ++k) b[k] = 3.0e38f;

#pragma unroll 4
  for (int j = 0; j < 128; ++j) {
    float4 sj = sg[jb + j];
    float base = sqi + sqg[jb + j];
    float d2 = fmaf(m2w, sj.w, fmaf(m2z, sj.z, fmaf(m2y, sj.y, fmaf(m2x, sj.x, base))));
    u32 db = __float_as_uint(d2);
    float key = __uint_as_float((db & 0xFFFFFC00u) | (u32)(jb + j));
#pragma unroll
    for (int k = 15; k >= 1; --k) b[k] = __builtin_amdgcn_fmed3f(key, b[k - 1], b[k]);
    b[0] = fminf(key, b[0]);
  }

#pragma unroll
  for (int k = 0; k < 16; ++k) lists[(w * 64 + lane) * 17 + k] = b[k];
  __syncthreads();

  float c[16];
  if (w < 4) {
#pragma unroll
    for (int i = 0; i < 16; ++i)
      c[i] = fminf(b[i], lists[((w + 4) * 64 + lane) * 17 + (15 - i)]);
#pragma unroll
    for (int dd = 8; dd >= 1; dd >>= 1) {
#pragma unroll
      for (int i = 0; i < 16; ++i) {
        if ((i & dd) == 0) {
          float lo = fminf(c[i], c[i | dd]);
          float hi = fmaxf(c[i], c[i | dd]);
          c[i] = lo; c[i | dd] = hi;
        }
      }
    }
#pragma unroll
    for (int k = 0; k < 16; ++k) lists[(w * 64 + lane) * 17 + k] = c[k];
  }
  __syncthreads();
  if (w < 2) {
#pragma unroll
    for (int i = 0; i < 16; ++i)
      c[i] = fminf(c[i], lists[((w + 2) * 64 + lane) * 17 + (15 - i)]);
#pragma unroll
    for (int dd = 8; dd >= 1; dd >>= 1) {
#pragma unroll
      for (int i = 0; i < 16; ++i) {
        if ((i & dd) == 0) {
          float lo = fminf(c[i], c[i | dd]);
          float hi = fmaxf(c[i], c[i | dd]);
          c[i] = lo; c[i | dd] = hi;
        }
      }
    }
#pragma unroll
    for (int k = 0; k < 16; ++k) lists[(w * 64 + lane) * 17 + k] = c[k];
  }
  __syncthreads();
  if (w == 0) {
#pragma unroll
    for (int i = 0; i < 16; ++i) {
      float o = lists[(64 + lane) * 17 + (15 - i)];
      float kf = fminf(c[i], o);
      fk[lane * 17 + i] = kf;
      wk[lane * 17 + i] =
          __expf(-10.0f * __uint_as_float(__float_as_uint(kf) & 0xFFFFFC00u));
    }
  }
  __syncthreads();        // fk/wk ready; lists[] selection data dead

  // ---- aggregation: lane <-> (node, 8-dim chunk); no shuffles (R5 body)
  {
    const int q     = lane & 7;              // dim chunk (8 bf16 = 16 B)
    const int nodeA = w * 8 + (lane >> 3);   // 0..63
    const u16* __restrict__ hg = h_buf + (size_t)g * L * FLR;

    float m[8], xx[8];
#pragma unroll
    for (int j = 0; j < 8; ++j) { m[j] = 0.f; xx[j] = -3.0e38f; }

#pragma unroll 4
    for (int k = 0; k < 16; ++k) {
      u32 u    = __float_as_uint(fk[nodeA * 17 + k]);
      float wg = wk[nodeA * 17 + k];
      const uint4 hv = ((const uint4*)(hg + (size_t)(u & 1023u) * FLR))[q];
      u32 p[4] = {hv.x, hv.y, hv.z, hv.w};
#pragma unroll
      for (int d = 0; d < 4; ++d) {
        float lo = __uint_as_float(p[d] << 16) * wg;
        float hi = __uint_as_float(p[d] & 0xFFFF0000u) * wg;
        m[2 * d]     += lo;  xx[2 * d]     = fmaxf(xx[2 * d], lo);
        m[2 * d + 1] += hi;  xx[2 * d + 1] = fmaxf(xx[2 * d + 1], hi);
      }
    }

    uint4 om, ox;
    om.x = pack2(m[0] * 0.0625f, m[1] * 0.0625f);
    om.y = pack2(m[2] * 0.0625f, m[3] * 0.0625f);
    om.z = pack2(m[4] * 0.0625f, m[5] * 0.0625f);
    om.w = pack2(m[6] * 0.0625f, m[7] * 0.0625f);
    ox.x = pack2(xx[0], xx[1]); ox.y = pack2(xx[2], xx[3]);
    ox.z = pack2(xx[4], xx[5]); ox.w = pack2(xx[6], xx[7]);
    *(uint4*)(&agg_lds[nodeA * 136 + q * 8])       = om;
    *(uint4*)(&agg_lds[nodeA * 136 + FLR + q * 8]) = ox;
  }
  __syncthreads();

  // ---- output GEMM (R5 body)
  const int mt  = w & 3;
  const int ntb = (w >> 2) * 4;
  const int rowL = mt * 16 + (lane & 15);
  const int grow = g * L + nb0 + rowL;
  const int kq8 = (lane >> 4) * 8;

  f32x4 acc[4];
#pragma unroll
  for (int nt = 0; nt < 4; ++nt) acc[nt] = f32x4{0.f, 0.f, 0.f, 0.f};

  const float* xr = x + (size_t)grow * IN;
  const bf16x8* __restrict__ bp = (const bf16x8*)Bp;
  const int tileA = (g * 16 + blockIdx.x) * 4 + mt;

#pragma unroll
  for (int ks = 0; ks < 8; ++ks) {
    bf16x8 a;
    if (ks < 4) {
      if (xbf) {
        a = *(const bf16x8*)(xbf + (((size_t)tileA * 4 + ks) * 64 + lane) * 8);
      } else {
        float4 xa = *(const float4*)(xr + ks * 32 + kq8);
        float4 xb = *(const float4*)(xr + ks * 32 + kq8 + 4);
        union { __hip_bfloat162 h2[4]; bf16x8 v; } cv;
        cv.h2[0] = __float22bfloat162_rn(float2{xa.x, xa.y});
        cv.h2[1] = __float22bfloat162_rn(float2{xa.z, xa.w});
        cv.h2[2] = __float22bfloat162_rn(float2{xb.x, xb.y});
        cv.h2[3] = __float22bfloat162_rn(float2{xb.z, xb.w});
        a = cv.v;
      }
    } else {
      a = *(const bf16x8*)(&agg_lds[rowL * 136 + (ks - 4) * 32 + kq8]);
    }
#pragma unroll
    for (int nt = 0; nt < 4; ++nt) {
      bf16x8 bb = bp[((ntb + nt) * 8 + ks) * 64 + lane];
      acc[nt] = __builtin_amdgcn_mfma_f32_16x16x32_bf16(a, bb, acc[nt], 0, 0, 0);
    }
  }

  const int rbase = (lane >> 4) * 4;
  const int colO = lane & 15;
  const int mrow = g * L + nb0 + mt * 16;
#pragma unroll
  for (int nt = 0; nt < 4; ++nt) {
    float bias = bout[(ntb + nt) * 16 + colO];
#pragma unroll
    for (int r = 0; r < 4; ++r) {
      float v = acc[nt][r] + bias;
      out[(size_t)(mrow + rbase + r) * OUT + (ntb + nt) * 16 + colO] = fmaxf(v, 0.0f);
    }
  }
}

extern "C" void kernel_launch(void* const* d_in, const int* in_sizes, int n_in,
                              void* d_out, int out_size, void* d_ws, size_t ws_size,
                              hipStream_t stream) {
  const float* x    = (const float*)d_in[0];
  const float* Ws   = (const float*)d_in[1];
  const float* bs   = (const float*)d_in[2];
  const float* Wh   = (const float*)d_in[3];
  const float* bh   = (const float*)d_in[4];
  const float* Wout = (const float*)d_in[5];
  const float* bout = (const float*)d_in[6];
  float* out = (float*)d_out;

  char* ws = (char*)d_ws;
  float* s_buf = (float*)ws;                                      // 1 MiB
  u16*   h_buf = (u16*)(ws + (1 << 20));                          // 8 MiB
  u16*   Bp    = (u16*)(ws + (1 << 20) + (8 << 20));              // 64 KiB
  u16*   Whp   = (u16*)(ws + (1 << 20) + (8 << 20) + (64 << 10)); // 16 KiB
  float* sqb   = (float*)(ws + (1 << 20) + (8 << 20) + (80 << 10)); // 256 KiB
  u16*   xbf   = (ws_size >= (26u << 20)) ? (u16*)(ws + (10 << 20)) : nullptr;

  k_pack<<<17, 256, 0, stream>>>(Wout, Wh, Bp, Whp);
  k_sh<<<N / 64, 256, 0, stream>>>(x, Ws, bs, Whp, bh, s_buf, h_buf, xbf, sqb);
  dim3 gknn(L / 64, Bb);
  k_fused<<<gknn, 512, 0, stream>>>(s_buf, h_buf, x, Bp, xbf, sqb, bout, out);
}